// Round 8
// baseline (73.474 us; speedup 1.0000x reference)
//
#include <hip/hip_runtime.h>
#include <hip/hip_bf16.h>
#include <stdint.h>

// ComplexDFT256: out(65536x512) = X(65536x512) @ W^T, W = [[cos,-sin],[sin,cos]].
// R5 structure + NON-TEMPORAL epilogue stores (don't pollute L2/L3 with the
// 131 MB write stream so X stays L3-resident).

typedef __attribute__((ext_vector_type(8))) short bf16x8;
typedef __attribute__((ext_vector_type(4))) float f32x4;

#define KDIM 512
#define NDIM 512
#define BM 64

__device__ __forceinline__ ushort f2bf(float f) {
  union { float f; uint32_t u; } v; v.f = f;
  uint32_t r = (v.u + 0x7fffu + ((v.u >> 16) & 1u)) >> 16;  // RNE
  return (ushort)r;
}

// Fragment-ordered W: Wf[8*g .. 8*g+7], g = k5*2048 + nt*64 + lane, holds
// W[j = nt*16 + (lane&15)][k = k5*32 + (lane>>4)*8 + e]  (e = 0..7)
__global__ __launch_bounds__(512) void build_w_kernel(const float* __restrict__ cosk,
                                                      const float* __restrict__ sink,
                                                      ushort* __restrict__ Wf) {
  int g = blockIdx.x * 512 + threadIdx.x;   // 0..32767
  int lane = g & 63;
  int nt = (g >> 6) & 31;
  int j = nt * 16 + (lane & 15);
  int kbase = (g >> 11) * 32 + (lane >> 4) * 8;
  bf16x8 w8;
#pragma unroll
  for (int e = 0; e < 8; ++e) {
    int k = kbase + e;
    float v;
    if (j < 256) {
      v = (k < 256) ? cosk[(j << 8) + k] : -sink[(j << 8) + (k - 256)];
    } else {
      int jj = j - 256;
      v = (k < 256) ? sink[(jj << 8) + k] : cosk[(jj << 8) + (k - 256)];
    }
    w8[e] = (short)f2bf(v);
  }
  *reinterpret_cast<bf16x8*>(Wf + (size_t)g * 8) = w8;
}

__device__ __forceinline__ bf16x8 cvt8(f32x4 a, f32x4 b) {
  bf16x8 w8;
  w8[0] = (short)f2bf(a[0]); w8[1] = (short)f2bf(a[1]);
  w8[2] = (short)f2bf(a[2]); w8[3] = (short)f2bf(a[3]);
  w8[4] = (short)f2bf(b[0]); w8[5] = (short)f2bf(b[1]);
  w8[6] = (short)f2bf(b[2]); w8[7] = (short)f2bf(b[3]);
  return w8;
}

// Block = 64 batch rows x full 512 output cols, 8 waves (each 64 j x 64 b).
// X staged in double-buffered LDS (bf16, XOR-swizzled); W frags streamed from L2.
__global__ __launch_bounds__(512) void dft_gemm_kernel(const float* __restrict__ A,
                                                       const ushort* __restrict__ Wf,
                                                       float* __restrict__ out) {
  __shared__ ushort As[2][BM * 64];   // 2 x 8 KB

  const int tid  = threadIdx.x;
  const int lane = tid & 63;
  const int wid  = tid >> 6;            // 0..7
  const int m0   = blockIdx.x * BM;     // batch-row base
  const int c0   = wid * 64;            // j base for this wave

  // staging: 512 threads, each 8 floats (two f32x4) of one row per K-tile
  const int srow = tid >> 3;
  const int skq  = (tid & 7) * 8;
  const float* ap = A + (size_t)(m0 + srow) * KDIM + skq;
  const int swidx = (srow << 6) + (skq ^ ((srow & 7) << 3));

  const int lrow = lane & 15;
  const int lk8  = (lane >> 4) * 8;

  // W frag base: (k5*32 + nt)*512 + lane*8 elems; nt = c0/16 + mi, k5 = t*2 + kk
  const ushort* wp = Wf + (size_t)(c0 >> 4) * 512 + lane * 8;

  f32x4 acc[4][4] = {};   // acc[mi][ni]: mi = j-tile, ni = b-tile

  // ---- prologue: tile 0 -> LDS[0], tile 1 in flight ----
  f32x4 q0 = *reinterpret_cast<const f32x4*>(ap);
  f32x4 q1 = *reinterpret_cast<const f32x4*>(ap + 4);
  f32x4 p0 = *reinterpret_cast<const f32x4*>(ap + 64);
  f32x4 p1 = *reinterpret_cast<const f32x4*>(ap + 68);
  *reinterpret_cast<bf16x8*>(&As[0][swidx]) = cvt8(q0, q1);
  asm volatile("s_waitcnt lgkmcnt(0)" ::: "memory");
  __builtin_amdgcn_s_barrier();

#pragma unroll
  for (int t = 0; t < 8; ++t) {
    // 1) write next X tile to the other buffer (waits on p via auto vmcnt)
    if (t < 7)
      *reinterpret_cast<bf16x8*>(&As[(t + 1) & 1][swidx]) = cvt8(p0, p1);

    // 2) issue all 8 W frag loads for this K-step (coalesced 1KB streams from L2)
    bf16x8 wfr[2][4];
#pragma unroll
    for (int kk = 0; kk < 2; ++kk)
#pragma unroll
      for (int mi = 0; mi < 4; ++mi)
        wfr[kk][mi] = *reinterpret_cast<const bf16x8*>(
            wp + (size_t)((t * 2 + kk) * 32 + mi) * 512);

    // 3) issue X tile t+2 (lands ~1 full iteration later)
    if (t < 6) {
      p0 = *reinterpret_cast<const f32x4*>(ap + (t + 2) * 64);
      p1 = *reinterpret_cast<const f32x4*>(ap + (t + 2) * 64 + 4);
    }

    // 4) LDS reads + MFMAs
#pragma unroll
    for (int kk = 0; kk < 2; ++kk) {
      bf16x8 xfr[4];
#pragma unroll
      for (int ni = 0; ni < 4; ++ni) {
        int row = ni * 16 + lrow;
        int idx = (row << 6) + ((kk * 32 + lk8) ^ ((lrow & 7) << 3));
        xfr[ni] = *reinterpret_cast<const bf16x8*>(&As[t & 1][idx]);
      }
#pragma unroll
      for (int mi = 0; mi < 4; ++mi)
#pragma unroll
        for (int ni = 0; ni < 4; ++ni)
          acc[mi][ni] = __builtin_amdgcn_mfma_f32_16x16x32_bf16(
              wfr[kk][mi], xfr[ni], acc[mi][ni], 0, 0, 0);
    }

    // 5) single barrier per K-step; only LDS drained (vmem stays in flight)
    if (t < 7) {
      asm volatile("s_waitcnt lgkmcnt(0)" ::: "memory");
      __builtin_amdgcn_s_barrier();
    }
  }

  // ---- epilogue: non-temporal f32x4 stores (bypass L2/L3 allocation) ----
  const int jbase = c0 + (lane >> 4) * 4;
#pragma unroll
  for (int ni = 0; ni < 4; ++ni) {
    size_t rowb = (size_t)(m0 + ni * 16 + lrow) * NDIM;
#pragma unroll
    for (int mi = 0; mi < 4; ++mi) {
      f32x4* op = reinterpret_cast<f32x4*>(out + rowb + jbase + mi * 16);
      __builtin_nontemporal_store(acc[mi][ni], op);
    }
  }
}

extern "C" void kernel_launch(void* const* d_in, const int* in_sizes, int n_in,
                              void* d_out, int out_size, void* d_ws, size_t ws_size,
                              hipStream_t stream) {
  const float* x    = (const float*)d_in[0];   // (65536, 2, 256) fp32
  const float* cosk = (const float*)d_in[1];   // (256, 256) fp32
  const float* sink = (const float*)d_in[2];   // (256, 256) fp32
  float* out = (float*)d_out;                  // (65536, 512, 1) fp32
  ushort* Wf = (ushort*)d_ws;                  // 512 KB fragment-ordered W

  build_w_kernel<<<64, 512, 0, stream>>>(cosk, sink, Wf);
  dft_gemm_kernel<<<65536 / BM, 512, 0, stream>>>(x, Wf, out);
}